// Round 9
// baseline (398.001 us; speedup 1.0000x reference)
//
#include <hip/hip_runtime.h>
#include <hip/hip_bf16.h>

typedef __bf16 bf16_t;
typedef _Float16 f16_t;
typedef __bf16 bf16x8_t __attribute__((ext_vector_type(8)));
typedef _Float16 f16x4_t __attribute__((ext_vector_type(4)));
typedef float f32x4_t __attribute__((ext_vector_type(4)));

static constexpr int B_ = 2, S_ = 2048, D_ = 512, H_ = 8, DK_ = 64, DFF_ = 2048;
static constexpr int M_ = B_ * S_;  // 4096 tokens
static constexpr float QSCALE = 0.125f * 1.44269504f;  // 1/sqrt(dk) * log2(e)

#if __has_builtin(__builtin_amdgcn_mfma_f32_16x16x16_f16)
#define MFMA16F16 __builtin_amdgcn_mfma_f32_16x16x16_f16
#else
#define MFMA16F16 __builtin_amdgcn_mfma_f32_16x16x16f16
#endif

__device__ __forceinline__ unsigned pkbf(float a, float b) {
  union { bf16_t h; unsigned short u; } x, y;
  x.h = (bf16_t)a; y.h = (bf16_t)b;
  return (unsigned)x.u | ((unsigned)y.u << 16);
}

// async global->LDS, 16B per lane. LDS dest = wave-uniform base + lane*16.
__device__ __forceinline__ void async16(void* lds, const void* g) {
  __builtin_amdgcn_global_load_lds((const __attribute__((address_space(1))) void*)g,
                                   (__attribute__((address_space(3))) void*)lds,
                                   16, 0, 0);
}

// ---------------------------------------------------------------------------
// PREP mega-kernel (one dispatch):
//  [0,1024):    weight transpose fp32 W[K][N] -> bf16 Wt[N][K] (64x64 tiles)
//  [1024,2048): encoder fp32 -> bf16
//  [2048,3072): x fp32 -> bf16 + per-row (sum, sumsq)
//  [3072,3079): colsum(W), row-major streaming (fully coalesced)
//  [3079,3087): zero atomic stats for x1/x2
// ---------------------------------------------------------------------------
struct PrepArg {
  const float* W[10]; bf16_t* T[10];
  const float* enc; bf16_t* encb;
  const float* x; bf16_t* xb; float2* stats0;
  float* stats12;
  float* csum[7];  // saQ,saK,saV,caQ,caK,caV (512) + ffW1 (2048)
};

__global__ __launch_bounds__(256) void prep(PrepArg a) {
  __shared__ float T[64 * 65];
  const int bx = blockIdx.x, tid = threadIdx.x;
  if (bx < 1024) {  // ---- weight transpose ----
    const float* W; bf16_t* Wt; int K, N, k0, n0;
    if (bx < 512) { int wi = bx >> 6, t = bx & 63; W = a.W[wi]; Wt = a.T[wi]; K = 512; N = 512; k0 = (t >> 3) * 64; n0 = (t & 7) * 64; }
    else if (bx < 768) { int t = bx - 512; W = a.W[8]; Wt = a.T[8]; K = 512; N = 2048; k0 = (t & 7) * 64; n0 = (t >> 3) * 64; }
    else { int t = bx - 768; W = a.W[9]; Wt = a.T[9]; K = 2048; N = 512; k0 = (t & 31) * 64; n0 = (t >> 5) * 64; }
#pragma unroll
    for (int p = 0; p < 4; ++p) {
      int e = p * 1024 + tid * 4;
      int kr = e >> 6, nc = e & 63;
      float4 f = *(const float4*)(W + (long)(k0 + kr) * N + n0 + nc);
      T[kr * 65 + nc + 0] = f.x; T[kr * 65 + nc + 1] = f.y;
      T[kr * 65 + nc + 2] = f.z; T[kr * 65 + nc + 3] = f.w;
    }
    __syncthreads();
#pragma unroll
    for (int p = 0; p < 2; ++p) {
      int e = p * 2048 + tid * 8;
      int nr = e >> 6, kc = e & 63;
      alignas(16) bf16_t t8[8];
#pragma unroll
      for (int j = 0; j < 8; ++j) t8[j] = (bf16_t)T[(kc + j) * 65 + nr];
      *(uint4*)(Wt + (long)(n0 + nr) * K + k0 + kc) = *(uint4*)t8;
    }
  } else if (bx < 2048) {  // ---- enc convert ----
    const long i = ((long)(bx - 1024) * 256 + tid) * 8;
    float4 u = *(const float4*)(a.enc + i);
    float4 v = *(const float4*)(a.enc + i + 4);
    alignas(16) bf16_t t[8];
    t[0] = (bf16_t)u.x; t[1] = (bf16_t)u.y; t[2] = (bf16_t)u.z; t[3] = (bf16_t)u.w;
    t[4] = (bf16_t)v.x; t[5] = (bf16_t)v.y; t[6] = (bf16_t)v.z; t[7] = (bf16_t)v.w;
    *(uint4*)(a.encb + i) = *(uint4*)t;
  } else if (bx < 3072) {  // ---- x convert + row stats ----
    const int row = (bx - 2048) * 4 + (tid >> 6);
    const int lane = tid & 63;
    const float4* xr = (const float4*)(a.x + (long)row * D_);
    float4 v0 = xr[lane * 2], v1 = xr[lane * 2 + 1];
    float s = v0.x + v0.y + v0.z + v0.w + v1.x + v1.y + v1.z + v1.w;
    float ss = v0.x * v0.x + v0.y * v0.y + v0.z * v0.z + v0.w * v0.w +
               v1.x * v1.x + v1.y * v1.y + v1.z * v1.z + v1.w * v1.w;
#pragma unroll
    for (int m = 1; m < 64; m <<= 1) { s += __shfl_xor(s, m); ss += __shfl_xor(ss, m); }
    alignas(16) bf16_t y[8];
    y[0] = (bf16_t)v0.x; y[1] = (bf16_t)v0.y; y[2] = (bf16_t)v0.z; y[3] = (bf16_t)v0.w;
    y[4] = (bf16_t)v1.x; y[5] = (bf16_t)v1.y; y[6] = (bf16_t)v1.z; y[7] = (bf16_t)v1.w;
    ((uint4*)(a.xb + (long)row * D_))[lane] = *(uint4*)y;
    if (lane == 0) a.stats0[row] = make_float2(s, ss);
  } else if (bx < 3079) {  // ---- colsum, row-major streaming ----
    const int wsel = bx - 3072;
    const int map[6] = {0, 1, 2, 4, 5, 6};
    const float* Wsrc = (wsel < 6) ? a.W[map[wsel]] : a.W[8];
    float* dst = a.csum[wsel];
    if (wsel < 6) {  // N=512: thread owns 2 cols
      float ax = 0.f, ay = 0.f;
      const float2* p = (const float2*)Wsrc + tid;
      for (int k = 0; k < 512; ++k) { float2 v = p[(long)k * 256]; ax += v.x; ay += v.y; }
      ((float2*)dst)[tid] = make_float2(ax, ay);
    } else {  // N=2048: thread owns 8 cols
      float acc[8] = {0, 0, 0, 0, 0, 0, 0, 0};
      for (int k = 0; k < 512; ++k) {
        float4 u = *(const float4*)(Wsrc + (long)k * 2048 + tid * 8);
        float4 v = *(const float4*)(Wsrc + (long)k * 2048 + tid * 8 + 4);
        acc[0] += u.x; acc[1] += u.y; acc[2] += u.z; acc[3] += u.w;
        acc[4] += v.x; acc[5] += v.y; acc[6] += v.z; acc[7] += v.w;
      }
      *(float4*)(dst + tid * 8) = make_float4(acc[0], acc[1], acc[2], acc[3]);
      *(float4*)(dst + tid * 8 + 4) = make_float4(acc[4], acc[5], acc[6], acc[7]);
    }
  } else {  // ---- zero stats12 ----
    const int i = (bx - 3079) * 2048 + tid * 8;
    *(f32x4_t*)&a.stats12[i] = (f32x4_t){0.f, 0.f, 0.f, 0.f};
    *(f32x4_t*)&a.stats12[i + 4] = (f32x4_t){0.f, 0.f, 0.f, 0.f};
  }
}

// ---------------------------------------------------------------------------
__device__ __forceinline__ void ln_coef(float2 st, float ga, float gb,
                                        float& sc, float& sh) {
  const float mean = st.x * (1.0f / 512.0f);
  float var = (st.y - 512.0f * mean * mean) * (1.0f / 511.0f);
  var = fmaxf(var, 0.0f);
  sc = ga / (sqrtf(var) + 1e-6f);
  sh = gb - mean * sc;
}

// ---------------------------------------------------------------------------
// gemmQ: 64x64 tile, BK=64, K=512, LDS dbuf, 4 blocks/CU. LN fused via
// commute (csum != null). z == zvt -> writes Vt[bh][d][s] in fp16.
// ---------------------------------------------------------------------------
struct GQ {
  const bf16_t* A[3]; const bf16_t* Wt[3];
  const float* bias[3]; const float* csum[3];
  void* out[3]; float osc[3];
  const float2* stats; const float* ga; const float* gb;
  int N; int zvt;
};

template <int RELU>
__global__ __launch_bounds__(256, 4) void gemmQ(GQ a) {
  __shared__ bf16_t As[2][64 * 64];
  __shared__ bf16_t Bs[2][64 * 64];
  const int z = blockIdx.z;
  const bf16_t* A = a.A[z];
  const bf16_t* Wt = a.Wt[z];
  const float* bias = a.bias[z];
  const float* csum = a.csum[z];
  const int N = a.N;
  const int tid = threadIdx.x;
  const int wave = tid >> 6, lane = tid & 63, quad = lane >> 4, l15 = lane & 15;
  const long m0 = (long)blockIdx.x * 64;
  const long n0 = (long)blockIdx.y * 64;
  const int wm = (wave >> 1) * 32;
  const int wn = (wave & 1) * 32;

  const int r8 = lane >> 3;
  const int cg = (lane & 7) ^ r8;
  const bf16_t* Ab = A + m0 * 512 + cg * 8;
  const bf16_t* Bb = Wt + n0 * 512 + cg * 8;

  auto stage = [&](int buf, int k0) {
#pragma unroll
    for (int c = 0; c < 2; ++c) {
      const int row = wave * 16 + c * 8;
      async16(&As[buf][row * 64], Ab + (long)(row + r8) * 512 + k0);
      async16(&Bs[buf][row * 64], Bb + (long)(row + r8) * 512 + k0);
    }
  };

  f32x4_t acc[2][2];
#pragma unroll
  for (int i = 0; i < 2; ++i)
#pragma unroll
    for (int j = 0; j < 2; ++j) acc[i][j] = (f32x4_t){0.f, 0.f, 0.f, 0.f};

  stage(0, 0);
  for (int kt = 0; kt < 8; ++kt) {
    __syncthreads();
    if (kt + 1 < 8) stage((kt + 1) & 1, (kt + 1) * 64);
    const bf16_t* Al = &As[kt & 1][0];
    const bf16_t* Bl = &Bs[kt & 1][0];
#pragma unroll
    for (int ks = 0; ks < 2; ++ks) {
      const int sc = ((ks * 4 + quad) ^ (l15 & 7)) * 8;
      bf16x8_t af[2], bfr[2];
#pragma unroll
      for (int i = 0; i < 2; ++i) {
        af[i] = *(const bf16x8_t*)&Al[(wm + i * 16 + l15) * 64 + sc];
        bfr[i] = *(const bf16x8_t*)&Bl[(wn + i * 16 + l15) * 64 + sc];
      }
#pragma unroll
      for (int i = 0; i < 2; ++i)
#pragma unroll
        for (int j = 0; j < 2; ++j)
          acc[i][j] = __builtin_amdgcn_mfma_f32_16x16x32_bf16(af[i], bfr[j], acc[i][j], 0, 0, 0);
    }
  }

  const bool useln = (csum != nullptr);
  float scr[2][4], shr[2][4];
  if (useln) {
    const float gav = a.ga[0], gbv = a.gb[0];
#pragma unroll
    for (int i = 0; i < 2; ++i)
#pragma unroll
      for (int r = 0; r < 4; ++r) {
        const int row = (int)m0 + wm + i * 16 + quad * 4 + r;
        ln_coef(a.stats[row], gav, gbv, scr[i][r], shr[i][r]);
      }
  } else {
#pragma unroll
    for (int i = 0; i < 2; ++i)
#pragma unroll
      for (int r = 0; r < 4; ++r) { scr[i][r] = 1.f; shr[i][r] = 0.f; }
  }

  const bool isVt = (z == a.zvt);
  const float osc = a.osc[z];
#pragma unroll
  for (int i = 0; i < 2; ++i) {
#pragma unroll
    for (int j = 0; j < 2; ++j) {
      const int col = (int)n0 + wn + j * 16 + l15;
      const float cs = useln ? csum[col] : 0.f;
      const float bv = bias[col];
      float v[4];
#pragma unroll
      for (int r = 0; r < 4; ++r) {
        v[r] = scr[i][r] * acc[i][j][r] + shr[i][r] * cs + bv;
        if constexpr (RELU == 1) v[r] = fmaxf(v[r], 0.f);
      }
      if (isVt) {
        const int row0 = (int)m0 + wm + i * 16 + quad * 4;
        const int b = row0 >> 11, s = row0 & 2047;
        const long addr = ((long)(b * 8 + (col >> 6)) * 64 + (col & 63)) * 2048 + s;
        union { f16_t h[4]; uint2 u; } w;
#pragma unroll
        for (int r = 0; r < 4; ++r) w.h[r] = (f16_t)v[r];
        *(uint2*)((f16_t*)a.out[z] + addr) = w.u;
      } else {
        bf16_t* outp = (bf16_t*)a.out[z];
#pragma unroll
        for (int r = 0; r < 4; ++r) {
          const long row = m0 + wm + i * 16 + quad * 4 + r;
          outp[row * N + col] = (bf16_t)(v[r] * osc);
        }
      }
    }
  }
}

// ---------------------------------------------------------------------------
// gemmR: 64x64 tile, BK=64. out = acc + bias + res (fp32).
// STATS: bf16 copy + per-row atomic (sum, sumsq) for the next LN.
// ---------------------------------------------------------------------------
template <bool STATS>
__global__ __launch_bounds__(256, 4) void gemmR(const bf16_t* __restrict__ A, int K,
                                                const bf16_t* __restrict__ Wt,
                                                const float* __restrict__ bias,
                                                const float* __restrict__ res,
                                                float* __restrict__ out,
                                                bf16_t* __restrict__ outb,
                                                float* __restrict__ statsOut) {
  __shared__ bf16_t As[2][64 * 64];
  __shared__ bf16_t Bs[2][64 * 64];
  const int tid = threadIdx.x;
  const int wave = tid >> 6, lane = tid & 63, quad = lane >> 4, l15 = lane & 15;
  const long m0 = (long)blockIdx.x * 64;
  const long n0 = (long)blockIdx.y * 64;
  const int wm = (wave >> 1) * 32;
  const int wn = (wave & 1) * 32;

  const int r8 = lane >> 3;
  const int cg = (lane & 7) ^ r8;
  const bf16_t* Ab = A + m0 * (long)K + cg * 8;
  const bf16_t* Bb = Wt + n0 * (long)K + cg * 8;

  auto stage = [&](int buf, int k0) {
#pragma unroll
    for (int c = 0; c < 2; ++c) {
      const int row = wave * 16 + c * 8;
      async16(&As[buf][row * 64], Ab + (long)(row + r8) * K + k0);
      async16(&Bs[buf][row * 64], Bb + (long)(row + r8) * K + k0);
    }
  };

  f32x4_t acc[2][2];
#pragma unroll
  for (int i = 0; i < 2; ++i)
#pragma unroll
    for (int j = 0; j < 2; ++j) acc[i][j] = (f32x4_t){0.f, 0.f, 0.f, 0.f};

  const int KT = K >> 6;
  stage(0, 0);
  for (int kt = 0; kt < KT; ++kt) {
    __syncthreads();
    if (kt + 1 < KT) stage((kt + 1) & 1, (kt + 1) * 64);
    const bf16_t* Al = &As[kt & 1][0];
    const bf16_t* Bl = &Bs[kt & 1][0];
#pragma unroll
    for (int ks = 0; ks < 2; ++ks) {
      const int sc = ((ks * 4 + quad) ^ (l15 & 7)) * 8;
      bf16x8_t af[2], bfr[2];
#pragma unroll
      for (int i = 0; i < 2; ++i) {
        af[i] = *(const bf16x8_t*)&Al[(wm + i * 16 + l15) * 64 + sc];
        bfr[i] = *(const bf16x8_t*)&Bl[(wn + i * 16 + l15) * 64 + sc];
      }
#pragma unroll
      for (int i = 0; i < 2; ++i)
#pragma unroll
        for (int j = 0; j < 2; ++j)
          acc[i][j] = __builtin_amdgcn_mfma_f32_16x16x32_bf16(af[i], bfr[j], acc[i][j], 0, 0, 0);
    }
  }

#pragma unroll
  for (int i = 0; i < 2; ++i) {
    float rs[4] = {0.f, 0.f, 0.f, 0.f}, rq[4] = {0.f, 0.f, 0.f, 0.f};
#pragma unroll
    for (int j = 0; j < 2; ++j) {
      const int col = (int)n0 + wn + j * 16 + l15;
      const float bv = bias[col];
#pragma unroll
      for (int r = 0; r < 4; ++r) {
        const long row = m0 + wm + i * 16 + quad * 4 + r;
        const float v = acc[i][j][r] + bv + res[row * 512 + col];
        out[row * 512 + col] = v;
        if constexpr (STATS) {
          outb[row * 512 + col] = (bf16_t)v;
          rs[r] += v;
          rq[r] += v * v;
        }
      }
    }
    if constexpr (STATS) {
#pragma unroll
      for (int r = 0; r < 4; ++r) {
#pragma unroll
        for (int m = 1; m < 16; m <<= 1) {
          rs[r] += __shfl_xor(rs[r], m);
          rq[r] += __shfl_xor(rq[r], m);
        }
        if (l15 == 0) {
          const long row = m0 + wm + i * 16 + quad * 4 + r;
          atomicAdd(&statsOut[row * 2], rs[r]);
          atomicAdd(&statsOut[row * 2 + 1], rq[r]);
        }
      }
    }
  }
}

// ---------------------------------------------------------------------------
// Flash attention v8b: transposed-S, no-max exp2 softmax (Q pre-scaled),
// split-K(3), 128 q rows/block. PV via mfma_f32_16x16x16_f16 with
// A = V^T fragment (from LDS), B = P^T DIRECTLY from softmax registers
// (C-layout k=quad*4+r, q=l15 == K=16 B-layout) -> C[m=d][n=q], matching
// the v7 write convention (col=q=l15, row=d=quad*4+r). No P LDS roundtrip.
// ---------------------------------------------------------------------------
template <bool CAUSAL>
__global__ __launch_bounds__(256, 4) void flash_attn(const bf16_t* __restrict__ Q,
                                                     const bf16_t* __restrict__ Kg,
                                                     const f16_t* __restrict__ Vt,
                                                     float* __restrict__ po,
                                                     float* __restrict__ pl) {
  __shared__ bf16_t Ks[2][64 * 64];  // [k][d] swizzled (16B-chunk XOR)
  __shared__ f16_t Vs[2][64 * 64];   // [d][k] swizzled
  const int tid = threadIdx.x, wave = tid >> 6, lane = tid & 63;
  const int quad = lane >> 4, l15 = lane & 15;
  const int bh = blockIdx.y, b = bh >> 3, h = bh & 7;
  const int qt = CAUSAL ? (15 - (int)blockIdx.x) : (int)blockIdx.x;
  const int chunk = blockIdx.z;
  const int ntt = CAUSAL ? (2 * qt + 2) : 32;
  const int tstart = (chunk * ntt) / 3;
  const int tend = ((chunk + 1) * ntt) / 3;
  const int q0 = qt * 128;
  const long prow0 = ((long)(chunk * 16 + bh)) * 2048;

  if (tstart >= tend) {  // empty chunk: zero partials
    const long ob = (prow0 + q0) * 64;
#pragma unroll
    for (int p = 0; p < 8; ++p)
      *(f32x4_t*)&po[ob + (long)tid * 32 + p * 4] = (f32x4_t){0.f, 0.f, 0.f, 0.f};
    if (tid < 128) pl[prow0 + q0 + tid] = 0.f;
    return;
  }

  const int qw = q0 + wave * 32;
  const long base = (long)b * S_ * D_ + (long)h * DK_;
  const long vtbase = (long)bh * DK_ * S_;

  bf16x8_t qf[2][2];
#pragma unroll
  for (int qh = 0; qh < 2; ++qh)
#pragma unroll
    for (int ks = 0; ks < 2; ++ks)
      qf[qh][ks] = *(const bf16x8_t*)(Q + base + (long)(qw + qh * 16 + l15) * D_ + ks * 32 + quad * 8);

  const int r8 = lane >> 3;
  const int cg8 = (lane & 7) ^ r8;
  const bf16_t* Kb = Kg + base + cg8 * 8;
  const f16_t* Vb = Vt + vtbase + cg8 * 8;

  auto stage = [&](int buf, int t) {
    const int kk0 = t * 64;
#pragma unroll
    for (int c = 0; c < 2; ++c) {
      const int row = wave * 16 + c * 8;
      async16(&Ks[buf][row * 64], Kb + (long)(kk0 + row + r8) * D_);
      async16(&Vs[buf][row * 64], Vb + (long)(row + r8) * S_ + kk0);
    }
  };

  float li[2] = {0.f, 0.f};
  f32x4_t o[2][4];
#pragma unroll
  for (int qh = 0; qh < 2; ++qh)
#pragma unroll
    for (int db = 0; db < 4; ++db) o[qh][db] = (f32x4_t){0.f, 0.f, 0.f, 0.f};

  stage(0, tstart);
  for (int t = tstart; t < tend; ++t) {
    const int buf = (t - tstart) & 1;
    __syncthreads();
    if (t + 1 < tend) stage(buf ^ 1, t + 1);
    const bf16_t* Kt = &Ks[buf][0];
    const f16_t* Vl = &Vs[buf][0];
    const int kk0 = t * 64;

    f16x4_t pa[2][4];  // P^T fragments (B-operand of K=16 mfma = C-layout)
#pragma unroll
    for (int qh = 0; qh < 2; ++qh) {
      f32x4_t st[4];
#pragma unroll
      for (int nb = 0; nb < 4; ++nb) {
        f32x4_t acc = (f32x4_t){0.f, 0.f, 0.f, 0.f};
#pragma unroll
        for (int ks = 0; ks < 2; ++ks) {
          const int scf = ((ks * 4 + quad) ^ (l15 & 7)) * 8;
          const bf16x8_t kf = *(const bf16x8_t*)&Kt[(nb * 16 + l15) * 64 + scf];
          acc = __builtin_amdgcn_mfma_f32_16x16x32_bf16(kf, qf[qh][ks], acc, 0, 0, 0);
        }
        st[nb] = acc;
      }
      const bool domask = CAUSAL && (kk0 + 63 > qw + qh * 16);
#pragma unroll
      for (int nb = 0; nb < 4; ++nb) {
#pragma unroll
        for (int r = 0; r < 4; ++r) {
          float v = st[nb][r];
          if (domask && (kk0 + nb * 16 + quad * 4 + r > qw + qh * 16 + l15)) v = -1e30f;
          const float p = exp2f(v);
          st[nb][r] = p;
          li[qh] += p;
        }
        pa[qh][nb] = (f16x4_t){(f16_t)st[nb][0], (f16_t)st[nb][1],
                               (f16_t)st[nb][2], (f16_t)st[nb][3]};
      }
    }

    // PV: O^T = V^T P^T. A = V^T frag (m=d_local=l15, k=quad*4+j from LDS),
    // B = P^T frag (k=quad*4+j, n=q=l15) = softmax registers directly.
#pragma unroll
    for (int k4 = 0; k4 < 4; ++k4) {
#pragma unroll
      for (int db = 0; db < 4; ++db) {
        const int row = db * 16 + l15;
        const int c = 2 * k4 + (quad >> 1);
        const f16x4_t vf = *(const f16x4_t*)&Vl[row * 64 + ((c ^ (l15 & 7)) * 8) + (quad & 1) * 4];
#pragma unroll
        for (int qh = 0; qh < 2; ++qh)
          o[qh][db] = MFMA16F16(vf, pa[qh][k4], o[qh][db], 0, 0, 0);
      }
    }
  }

#pragma unroll
  for (int qh = 0; qh < 2; ++qh) {
    li[qh] += __shfl_xor(li[qh], 16);
    li[qh] += __shfl_xor(li[qh], 32);
    const long pr = prow0 + qw + qh * 16 + l15;
#pragma unroll
    for (int db = 0; db < 4; ++db)
      *(f32x4_t*)&po[pr * 64 + db * 16 + quad * 4] = o[qh][db];
    if (quad == 0) pl[pr] = li[qh];
  }
}

// ---------------------------------------------------------------------------
// Merge 3 split-K partials: out = (o0+o1+o2)/(l0+l1+l2) -> bf16 [token][512].
// ---------------------------------------------------------------------------
__global__ __launch_bounds__(256) void merge3(const float* __restrict__ po,
                                              const float* __restrict__ pl,
                                              bf16_t* __restrict__ O) {
  const int qt = blockIdx.x, bh = blockIdx.y, b = bh >> 3, h = bh & 7;
  const int t = threadIdx.x;
  const int q = qt * 64 + (t >> 2), d0 = (t & 3) * 16;
  const long r0 = (long)bh * 2048 + q;
  const long r1 = (long)(16 + bh) * 2048 + q;
  const long r2 = (long)(32 + bh) * 2048 + q;
  const float inv = 1.0f / (pl[r0] + pl[r1] + pl[r2]);
  alignas(16) bf16_t out[16];
#pragma unroll
  for (int j = 0; j < 4; ++j) {
    f32x4_t x0 = *(const f32x4_t*)&po[r0 * 64 + d0 + j * 4];
    f32x4_t x1 = *(const f32x4_t*)&po[r1 * 64 + d0 + j * 4];
    f32x4_t x2 = *(const f32x4_t*)&po[r2 * 64 + d0 + j * 4];
#pragma unroll
    for (int r = 0; r < 4; ++r) out[j * 4 + r] = (bf16_t)((x0[r] + x1[r] + x2[r]) * inv);
  }
  const long row = (long)b * S_ + q;
  *(uint4*)(O + row * D_ + h * DK_ + d0) = *(uint4*)&out[0];
  *(uint4*)(O + row * D_ + h * DK_ + d0 + 8) = *(uint4*)&out[8];
}

// ---------------------------------------------------------------------------
extern "C" void kernel_launch(void* const* d_in, const int* in_sizes, int n_in,
                              void* d_out, int out_size, void* d_ws, size_t ws_size,
                              hipStream_t stream) {
  const float* x    = (const float*)d_in[0];
  const float* enc  = (const float*)d_in[1];
  const float* saWq = (const float*)d_in[4];  const float* sabq = (const float*)d_in[5];
  const float* saWk = (const float*)d_in[6];  const float* sabk = (const float*)d_in[7];
  const float* saWv = (const float*)d_in[8];  const float* sabv = (const float*)d_in[9];
  const float* saWo = (const float*)d_in[10]; const float* sabo = (const float*)d_in[11];
  const float* caWq = (const float*)d_in[12]; const float* cabq = (const float*)d_in[13];
  const float* caWk = (const float*)d_in[14]; const float* cabk = (const float*)d_in[15];
  const float* caWv = (const float*)d_in[16]; const float* cabv = (const float*)d_in[17];
  const float* caWo = (const float*)d_in[18]; const float* cabo = (const float*)d_in[19];
  const float* ffW1 = (const float*)d_in[20]; const float* ffb1 = (const float*)d_in[21];
  const float* ffW2 = (const float*)d_in[22]; const float* ffb2 = (const float*)d_in[23];
  const float* ln0a = (const float*)d_in[24]; const float* ln0b = (const float*)d_in[25];
  const float* ln1a = (const float*)d_in[26]; const float* ln1b = (const float*)d_in[27];
  const float* ln2a = (const float*)d_in[28]; const float* ln2b = (const float*)d_in[29];

  char* ws = (char*)d_ws;
  size_t off = 0;
  auto alloc = [&](size_t bytes) -> void* {
    void* p = ws + off;
    off += (bytes + 255) & ~(size_t)255;
    return p;
  };
  bf16_t* wt_saq = (bf16_t*)alloc(512 * 512 * 2);
  bf16_t* wt_sak = (bf16_t*)alloc(512 * 512 * 2);
  bf16_t* wt_sav = (bf16_t*)alloc(512 * 512 * 2);
  bf16_t* wt_sao = (bf16_t*)alloc(512 * 512 * 2);
  bf16_t* wt_caq = (bf16_t*)alloc(512 * 512 * 2);
  bf16_t* wt_cak = (bf16_t*)alloc(512 * 512 * 2);
  bf16_t* wt_cav = (bf16_t*)alloc(512 * 512 * 2);
  bf16_t* wt_cao = (bf16_t*)alloc(512 * 512 * 2);
  bf16_t* wt_f1  = (bf16_t*)alloc((size_t)512 * 2048 * 2);
  bf16_t* wt_f2  = (bf16_t*)alloc((size_t)2048 * 512 * 2);
  bf16_t* enc_b  = (bf16_t*)alloc((size_t)M_ * D_ * 2);
  bf16_t* xb     = (bf16_t*)alloc((size_t)M_ * D_ * 2);
  bf16_t* qb     = (bf16_t*)alloc((size_t)M_ * D_ * 2);
  bf16_t* kb     = (bf16_t*)alloc((size_t)M_ * D_ * 2);
  f16_t*  vtb    = (f16_t*)alloc((size_t)M_ * D_ * 2);
  bf16_t* attnb  = (bf16_t*)alloc((size_t)M_ * D_ * 2);
  // po (25,165,824 B) aliases [hid | x2] exactly — dead before hid/x2 written
  bf16_t* hid    = (bf16_t*)alloc((size_t)M_ * DFF_ * 2);  // 16,777,216
  float*  x2     = (float*)alloc((size_t)M_ * D_ * 4);     //  8,388,608
  float*  x1     = (float*)alloc((size_t)M_ * D_ * 4);
  bf16_t* x1b    = (bf16_t*)alloc((size_t)M_ * D_ * 2);
  bf16_t* x2b    = (bf16_t*)alloc((size_t)M_ * D_ * 2);
  float*  pl     = (float*)alloc(3 * 16 * 2048 * 4);
  float2* stats0 = (float2*)alloc(4096 * 8);
  float*  stats12= (float*)alloc(2 * 4096 * 2 * 4);
  float*  cs_saq = (float*)alloc(512 * 4);
  float*  cs_sak = (float*)alloc(512 * 4);
  float*  cs_sav = (float*)alloc(512 * 4);
  float*  cs_caq = (float*)alloc(512 * 4);
  float*  cs_cak = (float*)alloc(512 * 4);
  float*  cs_cav = (float*)alloc(512 * 4);
  float*  cs_f1  = (float*)alloc(2048 * 4);
  float*  po     = (float*)hid;
  float*  stats1 = stats12;
  float*  stats2 = stats12 + 8192;

  // ---- 1. prep ----
  {
    PrepArg a;
    a.W[0] = saWq; a.T[0] = wt_saq; a.W[1] = saWk; a.T[1] = wt_sak;
    a.W[2] = saWv; a.T[2] = wt_sav; a.W[3] = saWo; a.T[3] = wt_sao;
    a.W[4] = caWq; a.T[4] = wt_caq; a.W[5] = caWk; a.T[5] = wt_cak;
    a.W[6] = caWv; a.T[6] = wt_cav; a.W[7] = caWo; a.T[7] = wt_cao;
    a.W[8] = ffW1; a.T[8] = wt_f1;  a.W[9] = ffW2; a.T[9] = wt_f2;
    a.enc = enc; a.encb = enc_b; a.x = x; a.xb = xb; a.stats0 = stats0;
    a.stats12 = stats12;
    a.csum[0] = cs_saq; a.csum[1] = cs_sak; a.csum[2] = cs_sav;
    a.csum[3] = cs_caq; a.csum[4] = cs_cak; a.csum[5] = cs_cav;
    a.csum[6] = cs_f1;
    prep<<<3087, 256, 0, stream>>>(a);
  }

  // ---- 2. QKV self (LN fused; V -> Vt fp16 directly) ----
  {
    GQ g;
    g.A[0] = xb; g.A[1] = xb; g.A[2] = xb;
    g.Wt[0] = wt_saq; g.Wt[1] = wt_sak; g.Wt[2] = wt_sav;
    g.bias[0] = sabq; g.bias[1] = sabk; g.bias[2] = sabv;
    g.csum[0] = cs_saq; g.csum[1] = cs_sak; g.csum[2] = cs_sav;
    g.out[0] = qb; g.out[1] = kb; g.out[2] = vtb;
    g.osc[0] = QSCALE; g.osc[1] = 1.f; g.osc[2] = 1.f;
    g.stats = stats0; g.ga = ln0a; g.gb = ln0b; g.N = 512; g.zvt = 2;
    gemmQ<0><<<dim3(64, 8, 3), 256, 0, stream>>>(g);
  }
  // ---- 3-4. self attention + merge ----
  flash_attn<true><<<dim3(16, 16, 3), 256, 0, stream>>>(qb, kb, vtb, po, pl);
  merge3<<<dim3(32, 16), 256, 0, stream>>>(po, pl, attnb);
  // ---- 5. self out-proj: x1 = x + attn@Wo + bo ----
  gemmR<true><<<dim3(64, 8), 256, 0, stream>>>(attnb, 512, wt_sao, sabo, x, x1, x1b, stats1);

  // ---- 6. QKV cross (Q from ln(x1); K,V from raw encoder) ----
  {
    GQ g;
    g.A[0] = x1b; g.A[1] = enc_b; g.A[2] = enc_b;
    g.Wt[0] = wt_caq; g.Wt[1] = wt_cak; g.Wt[2] = wt_cav;
    g.bias[0] = cabq; g.bias[1] = cabk; g.bias[2] = cabv;
    g.csum[0] = cs_caq; g.csum[1] = nullptr; g.csum[2] = nullptr;
    g.out[0] = qb; g.out[1] = kb; g.out[2] = vtb;
    g.osc[0] = QSCALE; g.osc[1] = 1.f; g.osc[2] = 1.f;
    g.stats = (const float2*)stats1; g.ga = ln1a; g.gb = ln1b; g.N = 512; g.zvt = 2;
    gemmQ<0><<<dim3(64, 8, 3), 256, 0, stream>>>(g);
  }
  // ---- 7-8. cross attention + merge ----
  flash_attn<false><<<dim3(16, 16, 3), 256, 0, stream>>>(qb, kb, vtb, po, pl);
  merge3<<<dim3(32, 16), 256, 0, stream>>>(po, pl, attnb);
  // ---- 9. cross out-proj: x2 = x1 + attn@Wo + bo ----
  gemmR<true><<<dim3(64, 8), 256, 0, stream>>>(attnb, 512, wt_cao, cabo, x1, x2, x2b, stats2);

  // ---- 10. FFN1: hid = relu(ln(x2)@W1 + b1) ----
  {
    GQ g;
    g.A[0] = x2b; g.Wt[0] = wt_f1; g.bias[0] = ffb1; g.csum[0] = cs_f1;
    g.out[0] = hid; g.osc[0] = 1.f;
    g.A[1] = x2b; g.Wt[1] = wt_f1; g.bias[1] = ffb1; g.csum[1] = cs_f1;
    g.out[1] = hid; g.osc[1] = 1.f;
    g.A[2] = x2b; g.Wt[2] = wt_f1; g.bias[2] = ffb1; g.csum[2] = cs_f1;
    g.out[2] = hid; g.osc[2] = 1.f;
    g.stats = (const float2*)stats2; g.ga = ln2a; g.gb = ln2b; g.N = 2048; g.zvt = -1;
    gemmQ<1><<<dim3(64, 32, 1), 256, 0, stream>>>(g);
  }
  // ---- 11. FFN2: out = x2 + hid@W2 + b2 ----
  gemmR<false><<<dim3(64, 8), 256, 0, stream>>>(hid, 2048, wt_f2, ffb2, x2, (float*)d_out, nullptr, nullptr);
}

// Round 10
// 360.044 us; speedup vs baseline: 1.1054x; 1.1054x over previous
//
#include <hip/hip_runtime.h>
#include <hip/hip_bf16.h>

typedef __bf16 bf16_t;
typedef _Float16 f16_t;
typedef __bf16 bf16x8_t __attribute__((ext_vector_type(8)));
typedef _Float16 f16x4_t __attribute__((ext_vector_type(4)));
typedef float f32x4_t __attribute__((ext_vector_type(4)));

static constexpr int B_ = 2, S_ = 2048, D_ = 512, H_ = 8, DK_ = 64, DFF_ = 2048;
static constexpr int M_ = B_ * S_;  // 4096 tokens
static constexpr float QSCALE = 0.125f * 1.44269504f;  // 1/sqrt(dk) * log2(e)

#if __has_builtin(__builtin_amdgcn_mfma_f32_16x16x16_f16)
#define MFMA16F16 __builtin_amdgcn_mfma_f32_16x16x16_f16
#else
#define MFMA16F16 __builtin_amdgcn_mfma_f32_16x16x16f16
#endif

__device__ __forceinline__ unsigned pkbf(float a, float b) {
  union { bf16_t h; unsigned short u; } x, y;
  x.h = (bf16_t)a; y.h = (bf16_t)b;
  return (unsigned)x.u | ((unsigned)y.u << 16);
}

// async global->LDS, 16B per lane. LDS dest = wave-uniform base + lane*16.
__device__ __forceinline__ void async16(void* lds, const void* g) {
  __builtin_amdgcn_global_load_lds((const __attribute__((address_space(1))) void*)g,
                                   (__attribute__((address_space(3))) void*)lds,
                                   16, 0, 0);
}

// ---------------------------------------------------------------------------
// PREP mega-kernel (one dispatch; csum/stats zeroed by prior hipMemsetAsync):
//  [0,1024):     weight transpose fp32 W[K][N] -> bf16 Wt[N][K] (64x64 tiles)
//  [1024,2048):  encoder fp32 -> bf16
//  [2048,3072):  x fp32 -> bf16 + per-row (sum, sumsq)
//  [3072,3168):  colsum 512-wide weights: 6 x 16 chunks of 32 rows, atomicAdd
//  [3168,3200):  colsum ffW1: 32 chunks of 16 rows, atomicAdd
// ---------------------------------------------------------------------------
struct PrepArg {
  const float* W[10]; bf16_t* T[10];
  const float* enc; bf16_t* encb;
  const float* x; bf16_t* xb; float2* stats0;
  float* csum[7];  // saQ,saK,saV,caQ,caK,caV (512) + ffW1 (2048)
};

__global__ __launch_bounds__(256) void prep(PrepArg a) {
  __shared__ float T[64 * 65];
  const int bx = blockIdx.x, tid = threadIdx.x;
  if (bx < 1024) {  // ---- weight transpose ----
    const float* W; bf16_t* Wt; int K, N, k0, n0;
    if (bx < 512) { int wi = bx >> 6, t = bx & 63; W = a.W[wi]; Wt = a.T[wi]; K = 512; N = 512; k0 = (t >> 3) * 64; n0 = (t & 7) * 64; }
    else if (bx < 768) { int t = bx - 512; W = a.W[8]; Wt = a.T[8]; K = 512; N = 2048; k0 = (t & 7) * 64; n0 = (t >> 3) * 64; }
    else { int t = bx - 768; W = a.W[9]; Wt = a.T[9]; K = 2048; N = 512; k0 = (t & 31) * 64; n0 = (t >> 5) * 64; }
#pragma unroll
    for (int p = 0; p < 4; ++p) {
      int e = p * 1024 + tid * 4;
      int kr = e >> 6, nc = e & 63;
      float4 f = *(const float4*)(W + (long)(k0 + kr) * N + n0 + nc);
      T[kr * 65 + nc + 0] = f.x; T[kr * 65 + nc + 1] = f.y;
      T[kr * 65 + nc + 2] = f.z; T[kr * 65 + nc + 3] = f.w;
    }
    __syncthreads();
#pragma unroll
    for (int p = 0; p < 2; ++p) {
      int e = p * 2048 + tid * 8;
      int nr = e >> 6, kc = e & 63;
      alignas(16) bf16_t t8[8];
#pragma unroll
      for (int j = 0; j < 8; ++j) t8[j] = (bf16_t)T[(kc + j) * 65 + nr];
      *(uint4*)(Wt + (long)(n0 + nr) * K + k0 + kc) = *(uint4*)t8;
    }
  } else if (bx < 2048) {  // ---- enc convert ----
    const long i = ((long)(bx - 1024) * 256 + tid) * 8;
    float4 u = *(const float4*)(a.enc + i);
    float4 v = *(const float4*)(a.enc + i + 4);
    alignas(16) bf16_t t[8];
    t[0] = (bf16_t)u.x; t[1] = (bf16_t)u.y; t[2] = (bf16_t)u.z; t[3] = (bf16_t)u.w;
    t[4] = (bf16_t)v.x; t[5] = (bf16_t)v.y; t[6] = (bf16_t)v.z; t[7] = (bf16_t)v.w;
    *(uint4*)(a.encb + i) = *(uint4*)t;
  } else if (bx < 3072) {  // ---- x convert + row stats ----
    const int row = (bx - 2048) * 4 + (tid >> 6);
    const int lane = tid & 63;
    const float4* xr = (const float4*)(a.x + (long)row * D_);
    float4 v0 = xr[lane * 2], v1 = xr[lane * 2 + 1];
    float s = v0.x + v0.y + v0.z + v0.w + v1.x + v1.y + v1.z + v1.w;
    float ss = v0.x * v0.x + v0.y * v0.y + v0.z * v0.z + v0.w * v0.w +
               v1.x * v1.x + v1.y * v1.y + v1.z * v1.z + v1.w * v1.w;
#pragma unroll
    for (int m = 1; m < 64; m <<= 1) { s += __shfl_xor(s, m); ss += __shfl_xor(ss, m); }
    alignas(16) bf16_t y[8];
    y[0] = (bf16_t)v0.x; y[1] = (bf16_t)v0.y; y[2] = (bf16_t)v0.z; y[3] = (bf16_t)v0.w;
    y[4] = (bf16_t)v1.x; y[5] = (bf16_t)v1.y; y[6] = (bf16_t)v1.z; y[7] = (bf16_t)v1.w;
    ((uint4*)(a.xb + (long)row * D_))[lane] = *(uint4*)y;
    if (lane == 0) a.stats0[row] = make_float2(s, ss);
  } else if (bx < 3168) {  // ---- colsum 512-wide: atomic partials ----
    const int b3 = bx - 3072;
    const int map[6] = {0, 1, 2, 4, 5, 6};
    const int wsel = b3 >> 4;
    const int k0r = (b3 & 15) * 32;
    const float* Wsrc = a.W[map[wsel]];
    float* dst = a.csum[wsel];
    float ax = 0.f, ay = 0.f;
    const float2* p = (const float2*)Wsrc + (long)k0r * 256 + tid;
#pragma unroll 4
    for (int k = 0; k < 32; ++k) { float2 v = p[(long)k * 256]; ax += v.x; ay += v.y; }
    atomicAdd(&dst[2 * tid], ax);
    atomicAdd(&dst[2 * tid + 1], ay);
  } else {  // ---- colsum ffW1: atomic partials ----
    const int k0r = (bx - 3168) * 16;
    const float* Wsrc = a.W[8];
    float* dst = a.csum[6];
    float acc[8] = {0, 0, 0, 0, 0, 0, 0, 0};
#pragma unroll 2
    for (int k = 0; k < 16; ++k) {
      float4 u = *(const float4*)(Wsrc + (long)(k0r + k) * 2048 + tid * 8);
      float4 v = *(const float4*)(Wsrc + (long)(k0r + k) * 2048 + tid * 8 + 4);
      acc[0] += u.x; acc[1] += u.y; acc[2] += u.z; acc[3] += u.w;
      acc[4] += v.x; acc[5] += v.y; acc[6] += v.z; acc[7] += v.w;
    }
#pragma unroll
    for (int j = 0; j < 8; ++j) atomicAdd(&dst[tid * 8 + j], acc[j]);
  }
}

// ---------------------------------------------------------------------------
__device__ __forceinline__ void ln_coef(float2 st, float ga, float gb,
                                        float& sc, float& sh) {
  const float mean = st.x * (1.0f / 512.0f);
  float var = (st.y - 512.0f * mean * mean) * (1.0f / 511.0f);
  var = fmaxf(var, 0.0f);
  sc = ga / (sqrtf(var) + 1e-6f);
  sh = gb - mean * sc;
}

// ---------------------------------------------------------------------------
// gemmQ: 64x64 tile, BK=64, K=512, LDS dbuf, 4 blocks/CU. LN fused via
// commute (csum != null). z == zvt -> writes Vt[bh][d][s] fp16 via LDS
// transpose (coalesced 32B s-contiguous stores, not 8B/4KB-stride scatters).
// ---------------------------------------------------------------------------
struct GQ {
  const bf16_t* A[3]; const bf16_t* Wt[3];
  const float* bias[3]; const float* csum[3];
  void* out[3]; float osc[3];
  const float2* stats; const float* ga; const float* gb;
  int N; int zvt;
};

template <int RELU>
__global__ __launch_bounds__(256, 4) void gemmQ(GQ a) {
  __shared__ bf16_t As[2][64 * 64];
  __shared__ bf16_t Bs[2][64 * 64];
  const int z = blockIdx.z;
  const bf16_t* A = a.A[z];
  const bf16_t* Wt = a.Wt[z];
  const float* bias = a.bias[z];
  const float* csum = a.csum[z];
  const int N = a.N;
  const int tid = threadIdx.x;
  const int wave = tid >> 6, lane = tid & 63, quad = lane >> 4, l15 = lane & 15;
  const long m0 = (long)blockIdx.x * 64;
  const long n0 = (long)blockIdx.y * 64;
  const int wm = (wave >> 1) * 32;
  const int wn = (wave & 1) * 32;

  const int r8 = lane >> 3;
  const int cg = (lane & 7) ^ r8;
  const bf16_t* Ab = A + m0 * 512 + cg * 8;
  const bf16_t* Bb = Wt + n0 * 512 + cg * 8;

  auto stage = [&](int buf, int k0) {
#pragma unroll
    for (int c = 0; c < 2; ++c) {
      const int row = wave * 16 + c * 8;
      async16(&As[buf][row * 64], Ab + (long)(row + r8) * 512 + k0);
      async16(&Bs[buf][row * 64], Bb + (long)(row + r8) * 512 + k0);
    }
  };

  f32x4_t acc[2][2];
#pragma unroll
  for (int i = 0; i < 2; ++i)
#pragma unroll
    for (int j = 0; j < 2; ++j) acc[i][j] = (f32x4_t){0.f, 0.f, 0.f, 0.f};

  stage(0, 0);
  for (int kt = 0; kt < 8; ++kt) {
    __syncthreads();
    if (kt + 1 < 8) stage((kt + 1) & 1, (kt + 1) * 64);
    const bf16_t* Al = &As[kt & 1][0];
    const bf16_t* Bl = &Bs[kt & 1][0];
#pragma unroll
    for (int ks = 0; ks < 2; ++ks) {
      const int sc = ((ks * 4 + quad) ^ (l15 & 7)) * 8;
      bf16x8_t af[2], bfr[2];
#pragma unroll
      for (int i = 0; i < 2; ++i) {
        af[i] = *(const bf16x8_t*)&Al[(wm + i * 16 + l15) * 64 + sc];
        bfr[i] = *(const bf16x8_t*)&Bl[(wn + i * 16 + l15) * 64 + sc];
      }
#pragma unroll
      for (int i = 0; i < 2; ++i)
#pragma unroll
        for (int j = 0; j < 2; ++j)
          acc[i][j] = __builtin_amdgcn_mfma_f32_16x16x32_bf16(af[i], bfr[j], acc[i][j], 0, 0, 0);
    }
  }

  const bool useln = (csum != nullptr);
  float scr[2][4], shr[2][4];
  if (useln) {
    const float gav = a.ga[0], gbv = a.gb[0];
#pragma unroll
    for (int i = 0; i < 2; ++i)
#pragma unroll
      for (int r = 0; r < 4; ++r) {
        const int row = (int)m0 + wm + i * 16 + quad * 4 + r;
        ln_coef(a.stats[row], gav, gbv, scr[i][r], shr[i][r]);
      }
  } else {
#pragma unroll
    for (int i = 0; i < 2; ++i)
#pragma unroll
      for (int r = 0; r < 4; ++r) { scr[i][r] = 1.f; shr[i][r] = 0.f; }
  }

  const bool isVt = (z == a.zvt);
  const float osc = a.osc[z];
  f16_t* Tp = (f16_t*)&As[0][0];  // 64 x 72 f16 = 9216 B transpose buffer
  if (isVt) __syncthreads();      // all LDS reads drained before reuse

#pragma unroll
  for (int i = 0; i < 2; ++i) {
#pragma unroll
    for (int j = 0; j < 2; ++j) {
      const int col = (int)n0 + wn + j * 16 + l15;
      const float cs = useln ? csum[col] : 0.f;
      const float bv = bias[col];
      float v[4];
#pragma unroll
      for (int r = 0; r < 4; ++r) {
        v[r] = scr[i][r] * acc[i][j][r] + shr[i][r] * cs + bv;
        if constexpr (RELU == 1) v[r] = fmaxf(v[r], 0.f);
      }
      if (isVt) {
        const int dl = wn + j * 16 + l15;
        const int sl = wm + i * 16 + quad * 4;
#pragma unroll
        for (int r = 0; r < 4; ++r) Tp[dl * 72 + sl + r] = (f16_t)v[r];
      } else {
        bf16_t* outp = (bf16_t*)a.out[z];
#pragma unroll
        for (int r = 0; r < 4; ++r) {
          const long row = m0 + wm + i * 16 + quad * 4 + r;
          outp[row * N + col] = (bf16_t)(v[r] * osc);
        }
      }
    }
  }

  if (isVt) {
    __syncthreads();
    const int dl = tid >> 2, sc4 = (tid & 3) * 16;
    alignas(16) f16_t t16[16];
#pragma unroll
    for (int j = 0; j < 16; ++j) t16[j] = Tp[dl * 72 + sc4 + j];
    const int b = (int)(m0 >> 11), sbase = (int)(m0 & 2047);
    const int dg = (int)n0 + dl;
    const int h = dg >> 6, dih = dg & 63;
    f16_t* dstp = (f16_t*)a.out[z] + ((long)(b * 8 + h) * 64 + dih) * 2048 + sbase + sc4;
    *(uint4*)dstp = *(uint4*)&t16[0];
    *(uint4*)(dstp + 8) = *(uint4*)&t16[8];
  }
}

// ---------------------------------------------------------------------------
// gemmR: 64x64 tile, BK=64. out = acc + bias + res (fp32).
// STATS: bf16 copy + per-row atomic (sum, sumsq) for the next LN.
// ---------------------------------------------------------------------------
template <bool STATS>
__global__ __launch_bounds__(256, 4) void gemmR(const bf16_t* __restrict__ A, int K,
                                                const bf16_t* __restrict__ Wt,
                                                const float* __restrict__ bias,
                                                const float* __restrict__ res,
                                                float* __restrict__ out,
                                                bf16_t* __restrict__ outb,
                                                float* __restrict__ statsOut) {
  __shared__ bf16_t As[2][64 * 64];
  __shared__ bf16_t Bs[2][64 * 64];
  const int tid = threadIdx.x;
  const int wave = tid >> 6, lane = tid & 63, quad = lane >> 4, l15 = lane & 15;
  const long m0 = (long)blockIdx.x * 64;
  const long n0 = (long)blockIdx.y * 64;
  const int wm = (wave >> 1) * 32;
  const int wn = (wave & 1) * 32;

  const int r8 = lane >> 3;
  const int cg = (lane & 7) ^ r8;
  const bf16_t* Ab = A + m0 * (long)K + cg * 8;
  const bf16_t* Bb = Wt + n0 * (long)K + cg * 8;

  auto stage = [&](int buf, int k0) {
#pragma unroll
    for (int c = 0; c < 2; ++c) {
      const int row = wave * 16 + c * 8;
      async16(&As[buf][row * 64], Ab + (long)(row + r8) * K + k0);
      async16(&Bs[buf][row * 64], Bb + (long)(row + r8) * K + k0);
    }
  };

  f32x4_t acc[2][2];
#pragma unroll
  for (int i = 0; i < 2; ++i)
#pragma unroll
    for (int j = 0; j < 2; ++j) acc[i][j] = (f32x4_t){0.f, 0.f, 0.f, 0.f};

  const int KT = K >> 6;
  stage(0, 0);
  for (int kt = 0; kt < KT; ++kt) {
    __syncthreads();
    if (kt + 1 < KT) stage((kt + 1) & 1, (kt + 1) * 64);
    const bf16_t* Al = &As[kt & 1][0];
    const bf16_t* Bl = &Bs[kt & 1][0];
#pragma unroll
    for (int ks = 0; ks < 2; ++ks) {
      const int sc = ((ks * 4 + quad) ^ (l15 & 7)) * 8;
      bf16x8_t af[2], bfr[2];
#pragma unroll
      for (int i = 0; i < 2; ++i) {
        af[i] = *(const bf16x8_t*)&Al[(wm + i * 16 + l15) * 64 + sc];
        bfr[i] = *(const bf16x8_t*)&Bl[(wn + i * 16 + l15) * 64 + sc];
      }
#pragma unroll
      for (int i = 0; i < 2; ++i)
#pragma unroll
        for (int j = 0; j < 2; ++j)
          acc[i][j] = __builtin_amdgcn_mfma_f32_16x16x32_bf16(af[i], bfr[j], acc[i][j], 0, 0, 0);
    }
  }

#pragma unroll
  for (int i = 0; i < 2; ++i) {
    float rs[4] = {0.f, 0.f, 0.f, 0.f}, rq[4] = {0.f, 0.f, 0.f, 0.f};
#pragma unroll
    for (int j = 0; j < 2; ++j) {
      const int col = (int)n0 + wn + j * 16 + l15;
      const float bv = bias[col];
#pragma unroll
      for (int r = 0; r < 4; ++r) {
        const long row = m0 + wm + i * 16 + quad * 4 + r;
        const float v = acc[i][j][r] + bv + res[row * 512 + col];
        out[row * 512 + col] = v;
        if constexpr (STATS) {
          outb[row * 512 + col] = (bf16_t)v;
          rs[r] += v;
          rq[r] += v * v;
        }
      }
    }
    if constexpr (STATS) {
#pragma unroll
      for (int r = 0; r < 4; ++r) {
#pragma unroll
        for (int m = 1; m < 16; m <<= 1) {
          rs[r] += __shfl_xor(rs[r], m);
          rq[r] += __shfl_xor(rq[r], m);
        }
        if (l15 == 0) {
          const long row = m0 + wm + i * 16 + quad * 4 + r;
          atomicAdd(&statsOut[row * 2], rs[r]);
          atomicAdd(&statsOut[row * 2 + 1], rq[r]);
        }
      }
    }
  }
}

// ---------------------------------------------------------------------------
// Flash attention v8b: transposed-S, no-max exp2 softmax (Q pre-scaled),
// split-K(3), 128 q rows/block. PV via mfma_f32_16x16x16_f16 with
// A = V^T fragment (from LDS), B = P^T directly from softmax registers.
// ---------------------------------------------------------------------------
template <bool CAUSAL>
__global__ __launch_bounds__(256, 4) void flash_attn(const bf16_t* __restrict__ Q,
                                                     const bf16_t* __restrict__ Kg,
                                                     const f16_t* __restrict__ Vt,
                                                     float* __restrict__ po,
                                                     float* __restrict__ pl) {
  __shared__ bf16_t Ks[2][64 * 64];  // [k][d] swizzled (16B-chunk XOR)
  __shared__ f16_t Vs[2][64 * 64];   // [d][k] swizzled
  const int tid = threadIdx.x, wave = tid >> 6, lane = tid & 63;
  const int quad = lane >> 4, l15 = lane & 15;
  const int bh = blockIdx.y, b = bh >> 3, h = bh & 7;
  const int qt = CAUSAL ? (15 - (int)blockIdx.x) : (int)blockIdx.x;
  const int chunk = blockIdx.z;
  const int ntt = CAUSAL ? (2 * qt + 2) : 32;
  const int tstart = (chunk * ntt) / 3;
  const int tend = ((chunk + 1) * ntt) / 3;
  const int q0 = qt * 128;
  const long prow0 = ((long)(chunk * 16 + bh)) * 2048;

  if (tstart >= tend) {  // empty chunk: zero partials
    const long ob = (prow0 + q0) * 64;
#pragma unroll
    for (int p = 0; p < 8; ++p)
      *(f32x4_t*)&po[ob + (long)tid * 32 + p * 4] = (f32x4_t){0.f, 0.f, 0.f, 0.f};
    if (tid < 128) pl[prow0 + q0 + tid] = 0.f;
    return;
  }

  const int qw = q0 + wave * 32;
  const long base = (long)b * S_ * D_ + (long)h * DK_;
  const long vtbase = (long)bh * DK_ * S_;

  bf16x8_t qf[2][2];
#pragma unroll
  for (int qh = 0; qh < 2; ++qh)
#pragma unroll
    for (int ks = 0; ks < 2; ++ks)
      qf[qh][ks] = *(const bf16x8_t*)(Q + base + (long)(qw + qh * 16 + l15) * D_ + ks * 32 + quad * 8);

  const int r8 = lane >> 3;
  const int cg8 = (lane & 7) ^ r8;
  const bf16_t* Kb = Kg + base + cg8 * 8;
  const f16_t* Vb = Vt + vtbase + cg8 * 8;

  auto stage = [&](int buf, int t) {
    const int kk0 = t * 64;
#pragma unroll
    for (int c = 0; c < 2; ++c) {
      const int row = wave * 16 + c * 8;
      async16(&Ks[buf][row * 64], Kb + (long)(kk0 + row + r8) * D_);
      async16(&Vs[buf][row * 64], Vb + (long)(row + r8) * S_ + kk0);
    }
  };

  float li[2] = {0.f, 0.f};
  f32x4_t o[2][4];
#pragma unroll
  for (int qh = 0; qh < 2; ++qh)
#pragma unroll
    for (int db = 0; db < 4; ++db) o[qh][db] = (f32x4_t){0.f, 0.f, 0.f, 0.f};

  stage(0, tstart);
  for (int t = tstart; t < tend; ++t) {
    const int buf = (t - tstart) & 1;
    __syncthreads();
    if (t + 1 < tend) stage(buf ^ 1, t + 1);
    const bf16_t* Kt = &Ks[buf][0];
    const f16_t* Vl = &Vs[buf][0];
    const int kk0 = t * 64;

    f16x4_t pa[2][4];  // P^T fragments (B-operand of K=16 mfma = C-layout)
#pragma unroll
    for (int qh = 0; qh < 2; ++qh) {
      f32x4_t st[4];
#pragma unroll
      for (int nb = 0; nb < 4; ++nb) {
        f32x4_t acc = (f32x4_t){0.f, 0.f, 0.f, 0.f};
#pragma unroll
        for (int ks = 0; ks < 2; ++ks) {
          const int scf = ((ks * 4 + quad) ^ (l15 & 7)) * 8;
          const bf16x8_t kf = *(const bf16x8_t*)&Kt[(nb * 16 + l15) * 64 + scf];
          acc = __builtin_amdgcn_mfma_f32_16x16x32_bf16(kf, qf[qh][ks], acc, 0, 0, 0);
        }
        st[nb] = acc;
      }
      const bool domask = CAUSAL && (kk0 + 63 > qw + qh * 16);
#pragma unroll
      for (int nb = 0; nb < 4; ++nb) {
#pragma unroll
        for (int r = 0; r < 4; ++r) {
          float v = st[nb][r];
          if (domask && (kk0 + nb * 16 + quad * 4 + r > qw + qh * 16 + l15)) v = -1e30f;
          const float p = exp2f(v);
          st[nb][r] = p;
          li[qh] += p;
        }
        pa[qh][nb] = (f16x4_t){(f16_t)st[nb][0], (f16_t)st[nb][1],
                               (f16_t)st[nb][2], (f16_t)st[nb][3]};
      }
    }

    // PV: O^T = V^T P^T. A = V^T frag, B = P^T frag (softmax regs).
#pragma unroll
    for (int k4 = 0; k4 < 4; ++k4) {
#pragma unroll
      for (int db = 0; db < 4; ++db) {
        const int row = db * 16 + l15;
        const int c = 2 * k4 + (quad >> 1);
        const f16x4_t vf = *(const f16x4_t*)&Vl[row * 64 + ((c ^ (l15 & 7)) * 8) + (quad & 1) * 4];
#pragma unroll
        for (int qh = 0; qh < 2; ++qh)
          o[qh][db] = MFMA16F16(vf, pa[qh][k4], o[qh][db], 0, 0, 0);
      }
    }
  }

#pragma unroll
  for (int qh = 0; qh < 2; ++qh) {
    li[qh] += __shfl_xor(li[qh], 16);
    li[qh] += __shfl_xor(li[qh], 32);
    const long pr = prow0 + qw + qh * 16 + l15;
#pragma unroll
    for (int db = 0; db < 4; ++db)
      *(f32x4_t*)&po[pr * 64 + db * 16 + quad * 4] = o[qh][db];
    if (quad == 0) pl[pr] = li[qh];
  }
}

// ---------------------------------------------------------------------------
// Merge 3 split-K partials: out = (o0+o1+o2)/(l0+l1+l2) -> bf16 [token][512].
// ---------------------------------------------------------------------------
__global__ __launch_bounds__(256) void merge3(const float* __restrict__ po,
                                              const float* __restrict__ pl,
                                              bf16_t* __restrict__ O) {
  const int qt = blockIdx.x, bh = blockIdx.y, b = bh >> 3, h = bh & 7;
  const int t = threadIdx.x;
  const int q = qt * 64 + (t >> 2), d0 = (t & 3) * 16;
  const long r0 = (long)bh * 2048 + q;
  const long r1 = (long)(16 + bh) * 2048 + q;
  const long r2 = (long)(32 + bh) * 2048 + q;
  const float inv = 1.0f / (pl[r0] + pl[r1] + pl[r2]);
  alignas(16) bf16_t out[16];
#pragma unroll
  for (int j = 0; j < 4; ++j) {
    f32x4_t x0 = *(const f32x4_t*)&po[r0 * 64 + d0 + j * 4];
    f32x4_t x1 = *(const f32x4_t*)&po[r1 * 64 + d0 + j * 4];
    f32x4_t x2 = *(const f32x4_t*)&po[r2 * 64 + d0 + j * 4];
#pragma unroll
    for (int r = 0; r < 4; ++r) out[j * 4 + r] = (bf16_t)((x0[r] + x1[r] + x2[r]) * inv);
  }
  const long row = (long)b * S_ + q;
  *(uint4*)(O + row * D_ + h * DK_ + d0) = *(uint4*)&out[0];
  *(uint4*)(O + row * D_ + h * DK_ + d0 + 8) = *(uint4*)&out[8];
}

// ---------------------------------------------------------------------------
extern "C" void kernel_launch(void* const* d_in, const int* in_sizes, int n_in,
                              void* d_out, int out_size, void* d_ws, size_t ws_size,
                              hipStream_t stream) {
  const float* x    = (const float*)d_in[0];
  const float* enc  = (const float*)d_in[1];
  const float* saWq = (const float*)d_in[4];  const float* sabq = (const float*)d_in[5];
  const float* saWk = (const float*)d_in[6];  const float* sabk = (const float*)d_in[7];
  const float* saWv = (const float*)d_in[8];  const float* sabv = (const float*)d_in[9];
  const float* saWo = (const float*)d_in[10]; const float* sabo = (const float*)d_in[11];
  const float* caWq = (const float*)d_in[12]; const float* cabq = (const float*)d_in[13];
  const float* caWk = (const float*)d_in[14]; const float* cabk = (const float*)d_in[15];
  const float* caWv = (const float*)d_in[16]; const float* cabv = (const float*)d_in[17];
  const float* caWo = (const float*)d_in[18]; const float* cabo = (const float*)d_in[19];
  const float* ffW1 = (const float*)d_in[20]; const float* ffb1 = (const float*)d_in[21];
  const float* ffW2 = (const float*)d_in[22]; const float* ffb2 = (const float*)d_in[23];
  const float* ln0a = (const float*)d_in[24]; const float* ln0b = (const float*)d_in[25];
  const float* ln1a = (const float*)d_in[26]; const float* ln1b = (const float*)d_in[27];
  const float* ln2a = (const float*)d_in[28]; const float* ln2b = (const float*)d_in[29];

  char* ws = (char*)d_ws;
  size_t off = 0;
  auto alloc = [&](size_t bytes) -> void* {
    void* p = ws + off;
    off += (bytes + 255) & ~(size_t)255;
    return p;
  };
  bf16_t* wt_saq = (bf16_t*)alloc(512 * 512 * 2);
  bf16_t* wt_sak = (bf16_t*)alloc(512 * 512 * 2);
  bf16_t* wt_sav = (bf16_t*)alloc(512 * 512 * 2);
  bf16_t* wt_sao = (bf16_t*)alloc(512 * 512 * 2);
  bf16_t* wt_caq = (bf16_t*)alloc(512 * 512 * 2);
  bf16_t* wt_cak = (bf16_t*)alloc(512 * 512 * 2);
  bf16_t* wt_cav = (bf16_t*)alloc(512 * 512 * 2);
  bf16_t* wt_cao = (bf16_t*)alloc(512 * 512 * 2);
  bf16_t* wt_f1  = (bf16_t*)alloc((size_t)512 * 2048 * 2);
  bf16_t* wt_f2  = (bf16_t*)alloc((size_t)2048 * 512 * 2);
  bf16_t* enc_b  = (bf16_t*)alloc((size_t)M_ * D_ * 2);
  bf16_t* xb     = (bf16_t*)alloc((size_t)M_ * D_ * 2);
  bf16_t* qb     = (bf16_t*)alloc((size_t)M_ * D_ * 2);
  bf16_t* kb     = (bf16_t*)alloc((size_t)M_ * D_ * 2);
  f16_t*  vtb    = (f16_t*)alloc((size_t)M_ * D_ * 2);
  bf16_t* attnb  = (bf16_t*)alloc((size_t)M_ * D_ * 2);
  // po (25,165,824 B) aliases [hid | x2] exactly — dead before hid/x2 written
  bf16_t* hid    = (bf16_t*)alloc((size_t)M_ * DFF_ * 2);  // 16,777,216
  float*  x2     = (float*)alloc((size_t)M_ * D_ * 4);     //  8,388,608
  float*  x1     = (float*)alloc((size_t)M_ * D_ * 4);
  bf16_t* x1b    = (bf16_t*)alloc((size_t)M_ * D_ * 2);
  bf16_t* x2b    = (bf16_t*)alloc((size_t)M_ * D_ * 2);
  float*  pl     = (float*)alloc(3 * 16 * 2048 * 4);
  float2* stats0 = (float2*)alloc(4096 * 8);
  // zero region: csum (5120 floats) + stats12 (16384 floats) — one memset
  float*  zr     = (float*)alloc((5120 + 16384) * 4);
  float*  cs_saq = zr + 0;
  float*  cs_sak = zr + 512;
  float*  cs_sav = zr + 1024;
  float*  cs_caq = zr + 1536;
  float*  cs_cak = zr + 2048;
  float*  cs_cav = zr + 2560;
  float*  cs_f1  = zr + 3072;  // 2048 floats
  float*  stats1 = zr + 5120;  // 8192 floats
  float*  stats2 = zr + 13312; // 8192 floats
  float*  po     = (float*)hid;

  // ---- 0. zero csum+stats (graph-safe, same every call) ----
  hipMemsetAsync(zr, 0, (5120 + 16384) * 4, stream);

  // ---- 1. prep ----
  {
    PrepArg a;
    a.W[0] = saWq; a.T[0] = wt_saq; a.W[1] = saWk; a.T[1] = wt_sak;
    a.W[2] = saWv; a.T[2] = wt_sav; a.W[3] = saWo; a.T[3] = wt_sao;
    a.W[4] = caWq; a.T[4] = wt_caq; a.W[5] = caWk; a.T[5] = wt_cak;
    a.W[6] = caWv; a.T[6] = wt_cav; a.W[7] = caWo; a.T[7] = wt_cao;
    a.W[8] = ffW1; a.T[8] = wt_f1;  a.W[9] = ffW2; a.T[9] = wt_f2;
    a.enc = enc; a.encb = enc_b; a.x = x; a.xb = xb; a.stats0 = stats0;
    a.csum[0] = cs_saq; a.csum[1] = cs_sak; a.csum[2] = cs_sav;
    a.csum[3] = cs_caq; a.csum[4] = cs_cak; a.csum[5] = cs_cav;
    a.csum[6] = cs_f1;
    prep<<<3200, 256, 0, stream>>>(a);
  }

  // ---- 2. QKV self (LN fused; V -> Vt fp16, coalesced) ----
  {
    GQ g;
    g.A[0] = xb; g.A[1] = xb; g.A[2] = xb;
    g.Wt[0] = wt_saq; g.Wt[1] = wt_sak; g.Wt[2] = wt_sav;
    g.bias[0] = sabq; g.bias[1] = sabk; g.bias[2] = sabv;
    g.csum[0] = cs_saq; g.csum[1] = cs_sak; g.csum[2] = cs_sav;
    g.out[0] = qb; g.out[1] = kb; g.out[2] = vtb;
    g.osc[0] = QSCALE; g.osc[1] = 1.f; g.osc[2] = 1.f;
    g.stats = stats0; g.ga = ln0a; g.gb = ln0b; g.N = 512; g.zvt = 2;
    gemmQ<0><<<dim3(64, 8, 3), 256, 0, stream>>>(g);
  }
  // ---- 3-4. self attention + merge ----
  flash_attn<true><<<dim3(16, 16, 3), 256, 0, stream>>>(qb, kb, vtb, po, pl);
  merge3<<<dim3(32, 16), 256, 0, stream>>>(po, pl, attnb);
  // ---- 5. self out-proj: x1 = x + attn@Wo + bo ----
  gemmR<true><<<dim3(64, 8), 256, 0, stream>>>(attnb, 512, wt_sao, sabo, x, x1, x1b, stats1);

  // ---- 6. QKV cross (Q from ln(x1); K,V from raw encoder) ----
  {
    GQ g;
    g.A[0] = x1b; g.A[1] = enc_b; g.A[2] = enc_b;
    g.Wt[0] = wt_caq; g.Wt[1] = wt_cak; g.Wt[2] = wt_cav;
    g.bias[0] = cabq; g.bias[1] = cabk; g.bias[2] = cabv;
    g.csum[0] = cs_caq; g.csum[1] = nullptr; g.csum[2] = nullptr;
    g.out[0] = qb; g.out[1] = kb; g.out[2] = vtb;
    g.osc[0] = QSCALE; g.osc[1] = 1.f; g.osc[2] = 1.f;
    g.stats = (const float2*)stats1; g.ga = ln1a; g.gb = ln1b; g.N = 512; g.zvt = 2;
    gemmQ<0><<<dim3(64, 8, 3), 256, 0, stream>>>(g);
  }
  // ---- 7-8. cross attention + merge ----
  flash_attn<false><<<dim3(16, 16, 3), 256, 0, stream>>>(qb, kb, vtb, po, pl);
  merge3<<<dim3(32, 16), 256, 0, stream>>>(po, pl, attnb);
  // ---- 9. cross out-proj: x2 = x1 + attn@Wo + bo ----
  gemmR<true><<<dim3(64, 8), 256, 0, stream>>>(attnb, 512, wt_cao, cabo, x1, x2, x2b, stats2);

  // ---- 10. FFN1: hid = relu(ln(x2)@W1 + b1) ----
  {
    GQ g;
    g.A[0] = x2b; g.Wt[0] = wt_f1; g.bias[0] = ffb1; g.csum[0] = cs_f1;
    g.out[0] = hid; g.osc[0] = 1.f;
    g.A[1] = x2b; g.Wt[1] = wt_f1; g.bias[1] = ffb1; g.csum[1] = cs_f1;
    g.out[1] = hid; g.osc[1] = 1.f;
    g.A[2] = x2b; g.Wt[2] = wt_f1; g.bias[2] = ffb1; g.csum[2] = cs_f1;
    g.out[2] = hid; g.osc[2] = 1.f;
    g.stats = (const float2*)stats2; g.ga = ln2a; g.gb = ln2b; g.N = 2048; g.zvt = -1;
    gemmQ<1><<<dim3(64, 32, 1), 256, 0, stream>>>(g);
  }
  // ---- 11. FFN2: out = x2 + hid@W2 + b2 ----
  gemmR<false><<<dim3(64, 8), 256, 0, stream>>>(hid, 2048, wt_f2, ffb2, x2, (float*)d_out, nullptr, nullptr);
}